// Round 14
// baseline (118.776 us; speedup 1.0000x reference)
//
#include <hip/hip_runtime.h>

// MLA forward: B=2, T=2048, C=1024, LAT=256, H=16, D=64, causal, SCALE=1/8
#define SCALE 0.125f
#define SL 0.18033688011112042f  // SCALE * log2(e); folded into Q at up-projection

typedef __bf16 bf16x8 __attribute__((ext_vector_type(8)));
typedef short short4v __attribute__((ext_vector_type(4)));
typedef unsigned short u16x4 __attribute__((ext_vector_type(4)));
typedef float f32x4 __attribute__((ext_vector_type(4)));
typedef unsigned int uint2v __attribute__((ext_vector_type(2)));

__device__ __forceinline__ unsigned short f2b(float f) {
  unsigned u = __float_as_uint(f);
  u += 0x7fffu + ((u >> 16) & 1u);   // RNE; inputs here never NaN
  return (unsigned short)(u >> 16);
}
__device__ __forceinline__ float ex2(float x) {  // raw v_exp_f32 (2^x); -3e38 -> +0
  float r;
  asm("v_exp_f32 %0, %1" : "=v"(r) : "v"(x));
  return r;
}

#define GLB(p) ((__attribute__((address_space(1))) void*)(void*)(p))
#define LDSP(p) ((__attribute__((address_space(3))) void*)(p))

// ---------------- fused preprocessing (all weights transposed) ----------------
__global__ __launch_bounds__(256) void prep(
    const float* __restrict__ x, const float* __restrict__ wq_lat,
    const float* __restrict__ wk_lat, const float* __restrict__ wv_lat,
    const float* __restrict__ wq_h, const float* __restrict__ wk_h,
    const float* __restrict__ wv_h, const float* __restrict__ w_proj,
    unsigned short* __restrict__ x_bf, unsigned short* __restrict__ wlatT,
    unsigned short* __restrict__ whT, unsigned short* __restrict__ wpT) {
  __shared__ float tile[32][33];
  const int blk = blockIdx.x, tid = threadIdx.x;
  if (blk < 1024) {  // cast x: 4096x1024 fp32 -> bf16
    int i = blk * 256 + tid;
#pragma unroll
    for (int j = 0; j < 4; j++) {
      float4 v = ((const float4*)x)[i + j * 262144];
      u16x4 p;
      p.x = f2b(v.x); p.y = f2b(v.y); p.z = f2b(v.z); p.w = f2b(v.w);
      ((u16x4*)x_bf)[i + j * 262144] = p;
    }
  } else if (blk < 1792) {  // transpose wlat: [1024][256] -> wlatT[256][1024], x3
    int idx = blk - 1024;
    int z = idx >> 8, rem = idx & 255;
    const float* wsrc = z == 0 ? wq_lat : (z == 1 ? wk_lat : wv_lat);
    unsigned short* o = wlatT + z * 262144;
    int c0 = (rem & 7) * 32, r0 = (rem >> 3) * 32;
    int tx = tid & 31, ty = tid >> 5;
#pragma unroll
    for (int i = 0; i < 32; i += 8) tile[ty + i][tx] = wsrc[(r0 + ty + i) * 256 + c0 + tx];
    __syncthreads();
#pragma unroll
    for (int i = 0; i < 32; i += 8) o[(c0 + ty + i) * 1024 + r0 + tx] = f2b(tile[tx][ty + i]);
  } else if (blk < 2560) {  // transpose heads: [256][1024] -> whT[1024][256], x3
    int idx = blk - 1792;
    int z = idx >> 8, rem = idx & 255;
    const float* wsrc = z == 0 ? wq_h : (z == 1 ? wk_h : wv_h);
    unsigned short* o = whT + z * 262144;
    int c0 = (rem & 31) * 32, r0 = (rem >> 5) * 32;
    int tx = tid & 31, ty = tid >> 5;
#pragma unroll
    for (int i = 0; i < 32; i += 8) tile[ty + i][tx] = wsrc[(r0 + ty + i) * 1024 + c0 + tx];
    __syncthreads();
#pragma unroll
    for (int i = 0; i < 32; i += 8) o[(c0 + ty + i) * 256 + r0 + tx] = f2b(tile[tx][ty + i]);
  } else {  // transpose wproj: [1024][1024] -> wpT
    int idx = blk - 2560;
    int c0 = (idx & 31) * 32, r0 = (idx >> 5) * 32;
    int tx = tid & 31, ty = tid >> 5;
#pragma unroll
    for (int i = 0; i < 32; i += 8) tile[ty + i][tx] = w_proj[(r0 + ty + i) * 1024 + c0 + tx];
    __syncthreads();
#pragma unroll
    for (int i = 0; i < 32; i += 8) wpT[(c0 + ty + i) * 1024 + r0 + tx] = f2b(tile[tx][ty + i]);
  }
}

// ---------------- small GEMM (m97 structure): C[M,N] = A * BT^T ----------------
template <int MODE>  // 0: bf16 out; 2: fp32 out + bias
__global__ __launch_bounds__(256) void gemm_bt(
    const unsigned short* __restrict__ A0, const unsigned short* __restrict__ A1,
    const unsigned short* __restrict__ A2,
    const unsigned short* __restrict__ B0, const unsigned short* __restrict__ B1,
    const unsigned short* __restrict__ B2,
    void* __restrict__ C0, void* __restrict__ C1, void* __restrict__ C2,
    const float* __restrict__ bias, int M, int N, int K) {
  const int z = blockIdx.z;
  const unsigned short* A = z == 0 ? A0 : (z == 1 ? A1 : A2);
  const unsigned short* BT = z == 0 ? B0 : (z == 1 ? B1 : B2);
  void* C = z == 0 ? C0 : (z == 1 ? C1 : C2);

  __shared__ unsigned short lA[128 * 32];
  __shared__ unsigned short lB[128 * 32];

  const int t = threadIdx.x;
  const int n0 = blockIdx.x * 128;
  const int m0 = blockIdx.y * 128;
  const int lane = t & 63;
  const int wid = t >> 6;
  const int wr = wid >> 1, wc = wid & 1;
  const int lo = lane & 15, g = lane >> 4;

  f32x4 acc[4][4];
#pragma unroll
  for (int i = 0; i < 4; i++)
#pragma unroll
    for (int j = 0; j < 4; j++) acc[i][j] = (f32x4){0.f, 0.f, 0.f, 0.f};

  const unsigned short* ga = A + (size_t)(m0 + (t >> 2)) * K + (t & 3) * 8;
  const unsigned short* gb = BT + (size_t)(n0 + (t >> 2)) * K + (t & 3) * 8;
  const size_t rowK64 = (size_t)64 * K;

  for (int k0 = 0; k0 < K; k0 += 32) {
    __syncthreads();
    __builtin_amdgcn_global_load_lds(GLB(ga + k0), LDSP((char*)lA + t * 16), 16, 0, 0);
    __builtin_amdgcn_global_load_lds(GLB(ga + rowK64 + k0), LDSP((char*)lA + 4096 + t * 16), 16, 0, 0);
    __builtin_amdgcn_global_load_lds(GLB(gb + k0), LDSP((char*)lB + t * 16), 16, 0, 0);
    __builtin_amdgcn_global_load_lds(GLB(gb + rowK64 + k0), LDSP((char*)lB + 4096 + t * 16), 16, 0, 0);
    __syncthreads();

    bf16x8 af[4], bfr[4];
#pragma unroll
    for (int i = 0; i < 4; i++) {
      af[i] = *(const bf16x8*)&lA[(wr * 64 + i * 16 + lo) * 32 + g * 8];
      bfr[i] = *(const bf16x8*)&lB[(wc * 64 + i * 16 + lo) * 32 + g * 8];
    }
#pragma unroll
    for (int i = 0; i < 4; i++)
#pragma unroll
      for (int j = 0; j < 4; j++)
        acc[i][j] = __builtin_amdgcn_mfma_f32_16x16x32_bf16(af[i], bfr[j], acc[i][j], 0, 0, 0);
  }

  if constexpr (MODE == 2) {
    float* Cf = (float*)C;
#pragma unroll
    for (int i = 0; i < 4; i++) {
      int row0 = m0 + wr * 64 + i * 16 + g * 4;
#pragma unroll
      for (int j = 0; j < 4; j++) {
        int col = n0 + wc * 64 + j * 16 + lo;
        float bv = bias[col];
#pragma unroll
        for (int r = 0; r < 4; r++) Cf[(size_t)(row0 + r) * N + col] = acc[i][j][r] + bv;
      }
    }
  } else {
    unsigned short* Cb = (unsigned short*)C;
#pragma unroll
    for (int i = 0; i < 4; i++) {
      int row0 = m0 + wr * 64 + i * 16 + g * 4;
#pragma unroll
      for (int j = 0; j < 4; j++) {
        int col = n0 + wc * 64 + j * 16 + lo;
#pragma unroll
        for (int r = 0; r < 4; r++) Cb[(size_t)(row0 + r) * N + col] = f2b(acc[i][j][r]);
      }
    }
  }
}

// ---------------- 256x256 8-phase up-projection GEMM (K=256, NT=4 K-tiles) ----------------
__global__ __launch_bounds__(512) void gemm_up8(const unsigned short* __restrict__ A,
                                                const unsigned short* __restrict__ BT,
                                                unsigned short* __restrict__ Qo,
                                                unsigned short* __restrict__ Ko,
                                                unsigned short* __restrict__ Vo) {
  __shared__ char smem[131072];  // [dbuf][A0|A1|B0|B1] quarters of 16KB ([256 rows][64B])

  const int t = threadIdx.x;            // 0..511
  const int lane = t & 63;
  const int wid = t >> 6;               // 0..7
  const int wr = wid >> 2, wc = wid & 3;
  const int lo = lane & 15, g = lane >> 4;
  const int lin = blockIdx.x;           // 0..191
  const int xcd = lin & 7;
  const int slot = lin >> 3;            // 0..23
  const int by = (xcd << 1) | (slot >= 12 ? 1 : 0);
  const int bx = slot >= 12 ? slot - 12 : slot;   // 0..11
  const int m0 = by * 256;
  const int z = bx >> 2;                // 0:Q 1:K 2:V
  const int ncb = (bx & 3) * 256;
  const unsigned short* Az = A + (size_t)z * 1048576;   // lat z-slice [4096][256]
  const unsigned short* Bz = BT + (size_t)z * 262144;   // whT z-slice [1024][256]

  const int slog8 = (((t & 3) ^ ((t >> 2) & 3) ^ (((t >> 4) & 1) << 1)) << 3);
  const unsigned short *aS00, *aS01, *aS10, *aS11, *bS00, *bS01, *bS10, *bS11;
  {
    const int r = t >> 2;
    aS00 = Az + (size_t)(m0 + r) * 256 + slog8;
    aS01 = Az + (size_t)(m0 + r + 128) * 256 + slog8;
    aS10 = aS00 + 32;
    aS11 = aS01 + 32;
    bS00 = Bz + (size_t)(ncb + r) * 256 + slog8;
    bS01 = Bz + (size_t)(ncb + r + 128) * 256 + slog8;
    bS10 = bS00 + 32;
    bS11 = bS01 + 32;
  }
  char* dA0 = smem + t * 16;
  char* dA1 = smem + 16384 + t * 16;
  char* dB0 = smem + 32768 + t * 16;
  char* dB1 = smem + 49152 + t * 16;

  const int slotA = ((g ^ (lo & 3) ^ (((lo >> 2) & 1) << 1)) << 4);
  const char* aR = smem + (wr * 128 + lo) * 64 + slotA;
  const char* bR = smem + 32768 + (wc * 64 + lo) * 64 + slotA;

  f32x4 acc[8][4];
#pragma unroll
  for (int i = 0; i < 8; i++)
#pragma unroll
    for (int j = 0; j < 4; j++) acc[i][j] = (f32x4){0.f, 0.f, 0.f, 0.f};

#define STG(p0, p1, dst, D)                                                              \
  __builtin_amdgcn_global_load_lds(GLB(p0), LDSP(dst + (D)*65536), 16, 0, 0);            \
  __builtin_amdgcn_global_load_lds(GLB(p1), LDSP(dst + (D)*65536 + 8192), 16, 0, 0);     \
  p0 += 64; p1 += 64;

#define MF16(FRB, af, bf)                                                                \
  __builtin_amdgcn_s_setprio(1);                                                         \
  _Pragma("unroll") for (int i = 0; i < 4; i++)                                          \
  _Pragma("unroll") for (int j = 0; j < 4; j++)                                          \
      acc[(FRB) + i][j] = __builtin_amdgcn_mfma_f32_16x16x32_bf16(af[i], bf[j],          \
                                                                  acc[(FRB) + i][j], 0, 0, 0); \
  __builtin_amdgcn_s_setprio(0);

#define TILE(D, S)                                                                       \
  {                                                                                      \
    bf16x8 af[4], bf[4];                                                                 \
    _Pragma("unroll") for (int j = 0; j < 4; j++)                                        \
        bf[j] = *(const bf16x8*)(bR + (D)*65536 + j * 1024);                             \
    _Pragma("unroll") for (int i = 0; i < 4; i++)                                        \
        af[i] = *(const bf16x8*)(aR + (D)*65536 + i * 1024);                             \
    if (S) { STG(aS00, aS01, dA0, (D) ^ 1); }                                            \
    __builtin_amdgcn_s_barrier();                                                        \
    MF16(0, af, bf);                                                                     \
    __builtin_amdgcn_s_barrier();                                                        \
    _Pragma("unroll") for (int i = 0; i < 4; i++)                                        \
        af[i] = *(const bf16x8*)(aR + (D)*65536 + (4 + i) * 1024);                       \
    if (S) { STG(bS00, bS01, dB0, (D) ^ 1); }                                            \
    __builtin_amdgcn_s_barrier();                                                        \
    MF16(4, af, bf);                                                                     \
    if (S) { asm volatile("s_waitcnt vmcnt(4)" ::: "memory"); }                          \
    else   { asm volatile("s_waitcnt vmcnt(0)" ::: "memory"); }                          \
    __builtin_amdgcn_s_barrier();                                                        \
    _Pragma("unroll") for (int j = 0; j < 4; j++)                                        \
        bf[j] = *(const bf16x8*)(bR + (D)*65536 + 16384 + j * 1024);                     \
    _Pragma("unroll") for (int i = 0; i < 4; i++)                                        \
        af[i] = *(const bf16x8*)(aR + (D)*65536 + 16384 + i * 1024);                     \
    if (S) { STG(aS10, aS11, dA1, (D) ^ 1); }                                            \
    __builtin_amdgcn_s_barrier();                                                        \
    MF16(0, af, bf);                                                                     \
    __builtin_amdgcn_s_barrier();                                                        \
    _Pragma("unroll") for (int i = 0; i < 4; i++)                                        \
        af[i] = *(const bf16x8*)(aR + (D)*65536 + 16384 + (4 + i) * 1024);               \
    if (S) { STG(bS10, bS11, dB1, (D) ^ 1); }                                            \
    __builtin_amdgcn_s_barrier();                                                        \
    MF16(4, af, bf);                                                                     \
    if (S) { asm volatile("s_waitcnt vmcnt(4)" ::: "memory"); }                          \
    __builtin_amdgcn_s_barrier();                                                        \
  }

  { STG(aS00, aS01, dA0, 0); }
  { STG(bS00, bS01, dB0, 0); }
  { STG(aS10, aS11, dA1, 0); }
  { STG(bS10, bS11, dB1, 0); }
  asm volatile("s_waitcnt vmcnt(0)" ::: "memory");
  __builtin_amdgcn_s_barrier();

  // 4 K-tiles (K=256, BK=64): tiles 0..2 stage the next; tile 3 drains
  TILE(0, 1);
  TILE(1, 1);
  TILE(0, 1);
  TILE(1, 0);

#undef TILE
#undef MF16
#undef STG

  if (z < 2) {
    unsigned short* Cb = z == 0 ? Qo : Ko;
    const float scl = z == 0 ? SL : 1.0f;   // fold SCALE*log2e into Q
#pragma unroll
    for (int fr = 0; fr < 8; fr++) {
      int row0 = m0 + wr * 128 + fr * 16 + g * 4;
#pragma unroll
      for (int fc = 0; fc < 4; fc++) {
        int col = ncb + wc * 64 + fc * 16 + lo;
#pragma unroll
        for (int r = 0; r < 4; r++) Cb[(size_t)(row0 + r) * 1024 + col] = f2b(acc[fr][fc][r] * scl);
      }
    }
  } else {
#pragma unroll
    for (int fr = 0; fr < 8; fr++) {
      int row0 = m0 + wr * 128 + fr * 16 + g * 4;
      int bb = row0 >> 11, tloc = row0 & 2047;
#pragma unroll
      for (int fc = 0; fc < 4; fc++) {
        int col = ncb + wc * 64 + fc * 16 + lo;
        u16x4 pk;
#pragma unroll
        for (int r = 0; r < 4; r++) pk[r] = f2b(acc[fr][fc][r]);
        *(u16x4*)&Vo[((size_t)(bb * 1024) + col) * 2048 + tloc] = pk;
      }
    }
  }
}

// ---------------- flash attention: kv-quarter wave split ----------------
// 1024 blocks x 4 waves (R6 grid/schedule). Wave w owns kv rows w*16..w*16+15 of each
// 64-kv tile and computes ALL 64 q of the block (4 q-frags). Per wave per tile: 2 b128
// (K) + 4 b64 (V) -> block LDS reads drop 4x vs all-waves-read-all. Partial acc/lrun
// reduced across waves via LDS tree at the end (K/V buffers reused); w0 stores Y.
// Static-max softmax (Q pre-scaled by SL), native v_exp_f32.
__global__ __launch_bounds__(256) void attn_fwd(const unsigned short* __restrict__ Q,
                                                const unsigned short* __restrict__ K,
                                                const unsigned short* __restrict__ VT,
                                                unsigned short* __restrict__ Y) {
  __shared__ char smem[36864];  // [0,32K): lK[2][8KB] | lV[2][8KB]; [32K,36K): lrun xchg

  const int tid = threadIdx.x;
  const int w = tid >> 6;
  const int lane = tid & 63;
  const int lo = lane & 15, g = lane >> 4;
  const int lo7 = lo & 7;
  const int bid = blockIdx.x;
  const int bh = bid & 31;       // (b,h) -> fixed XCD (bid%8)
  const int code = bid >> 5;     // 0..31
  const int qq = code >> 3, kk = code & 7;
  // per-CU balanced: chunks {31-k, 16+k, 15-k, k} sum to 62 for all k
  const int chunk = qq == 0 ? 31 - kk : (qq == 1 ? 16 + kk : (qq == 2 ? 15 - kk : kk));
  const int b = bh >> 4, h = bh & 15;
  const int q0b = chunk * 64;    // block's 64 q rows (all waves)

  const unsigned short* Qb = Q + (size_t)(b * 2048) * 1024 + h * 64;
  const unsigned short* Kb = K + (size_t)(b * 2048) * 1024 + h * 64;
  const unsigned short* Vb = VT + (size_t)((b * 16 + h) * 64) * 2048;

  bf16x8 qf[4][2];
#pragma unroll
  for (int qfi = 0; qfi < 4; qfi++)
#pragma unroll
    for (int sp = 0; sp < 2; sp++)
      qf[qfi][sp] = *(const bf16x8*)(Qb + (size_t)(q0b + qfi * 16 + lo) * 1024 + sp * 32 + g * 8);

  const f32x4 z4 = (f32x4){0.f, 0.f, 0.f, 0.f};
  f32x4 acc[4][4];
#pragma unroll
  for (int qfi = 0; qfi < 4; qfi++)
#pragma unroll
    for (int dt = 0; dt < 4; dt++) acc[qfi][dt] = z4;
  f32x4 lrunv = z4;
  const int nt = chunk + 1;

  // K read bases: row = w*16 + lo -> +w*2048; swizzle uses (w*16+lo)&7 == lo&7
  const int koff = lo * 128 + ((g ^ lo7) << 4);
  char* kb0 = smem + w * 2048 + koff;
  char* kb1 = smem + w * 2048 + (koff ^ 64);
  // V read base for this wave's kv quarter (kvf = w)
  const int voff = lo * 128 + ((g ^ ((lo7 & 1) << 1)) << 3) + ((lo7 >> 1) << 5);
  char* vpw = smem + 16384 + (voff ^ (w << 5));

  const int r0s = tid >> 3, c0s = (tid & 7) ^ (r0s & 7);
  const unsigned short* sk0 = Kb + (size_t)r0s * 1024 + c0s * 8;
  const unsigned short* sk1 = sk0 + (size_t)32 * 1024;
  const unsigned short* sv0 = Vb + (size_t)r0s * 2048 + c0s * 8;
  const unsigned short* sv1 = sv0 + (size_t)32 * 2048;
  char* dk0 = smem + tid * 16;
  char* dk1 = smem + 4096 + tid * 16;
  char* dv0 = smem + 16384 + tid * 16;
  char* dv1 = smem + 20480 + tid * 16;

#define STAGE(BUF)                                                                        \
  __builtin_amdgcn_global_load_lds(GLB(sk0), LDSP(dk0 + (BUF)*8192), 16, 0, 0);           \
  __builtin_amdgcn_global_load_lds(GLB(sk1), LDSP(dk1 + (BUF)*8192), 16, 0, 0);           \
  __builtin_amdgcn_global_load_lds(GLB(sv0), LDSP(dv0 + (BUF)*8192), 16, 0, 0);           \
  __builtin_amdgcn_global_load_lds(GLB(sv1), LDSP(dv1 + (BUF)*8192), 16, 0, 0);           \
  sk0 += 65536; sk1 += 65536; sv0 += 64; sv1 += 64;

#define COMPUTE(k0v, BUF, MASKED)                                                         \
  {                                                                                       \
    bf16x8 kfA = *(const bf16x8*)(kb0 + (BUF)*8192);                                      \
    bf16x8 kfB = *(const bf16x8*)(kb1 + (BUF)*8192);                                      \
    short4v vf0 = *(const short4v*)(vpw + (BUF)*8192);                                    \
    short4v vf1 = *(const short4v*)(vpw + (BUF)*8192 + 2048);                             \
    short4v vf2 = *(const short4v*)(vpw + (BUF)*8192 + 4096);                             \
    short4v vf3 = *(const short4v*)(vpw + (BUF)*8192 + 6144);                             \
    const int tkb = (k0v) + (w << 4) + g * 4;                                             \
    _Pragma("unroll") for (int qfi = 0; qfi < 4; qfi++) {                                 \
      f32x4 st;                                                                           \
      __builtin_amdgcn_s_setprio(1);                                                      \
      st = __builtin_amdgcn_mfma_f32_16x16x32_bf16(kfA, qf[qfi][0], z4, 0, 0, 0);         \
      st = __builtin_amdgcn_mfma_f32_16x16x32_bf16(kfB, qf[qfi][1], st, 0, 0, 0);         \
      __builtin_amdgcn_s_setprio(0);                                                      \
      if (MASKED) {                                                                       \
        const int qg = q0b + qfi * 16 + lo;                                               \
        _Pragma("unroll") for (int r = 0; r < 4; r++)                                     \
            if (tkb + r > qg) st[r] = -3.0e38f;                                           \
      }                                                                                   \
      float p0 = ex2(st[0]);                                                              \
      float p1 = ex2(st[1]);                                                              \
      float p2 = ex2(st[2]);                                                              \
      float p3 = ex2(st[3]);                                                              \
      lrunv[qfi] += (p0 + p1) + (p2 + p3);                                                \
      uint2v pw;                                                                          \
      pw.x = __builtin_amdgcn_perm(__float_as_uint(p1), __float_as_uint(p0), 0x07060302u); \
      pw.y = __builtin_amdgcn_perm(__float_as_uint(p3), __float_as_uint(p2), 0x07060302u); \
      short4v pb = __builtin_bit_cast(short4v, pw);                                       \
      __builtin_amdgcn_s_setprio(1);                                                      \
      acc[qfi][0] = __builtin_amdgcn_mfma_f32_16x16x16bf16_1k(vf0, pb, acc[qfi][0], 0, 0, 0); \
      acc[qfi][1] = __builtin_amdgcn_mfma_f32_16x16x16bf16_1k(vf1, pb, acc[qfi][1], 0, 0, 0); \
      acc[qfi][2] = __builtin_amdgcn_mfma_f32_16x16x16bf16_1k(vf2, pb, acc[qfi][2], 0, 0, 0); \
      acc[qfi][3] = __builtin_amdgcn_mfma_f32_16x16x16bf16_1k(vf3, pb, acc[qfi][3], 0, 0, 0); \
      __builtin_amdgcn_s_setprio(0);                                                      \
    }                                                                                     \
  }

  STAGE(0);
  __syncthreads();
  int t = 0;
  for (; t + 2 <= nt - 1; t += 2) {
    STAGE(1);
    COMPUTE(t * 64, 0, false);
    __syncthreads();
    STAGE(0);
    COMPUTE(t * 64 + 64, 1, false);
    __syncthreads();
  }
  if (t < nt - 1) {
    STAGE(1);
    COMPUTE(t * 64, 0, false);
    __syncthreads();
    COMPUTE(t * 64 + 64, 1, true);
  } else {
    COMPUTE(t * 64, 0, true);
  }

  // ---- cross-wave reduction (acc, lrun) ----
  // g-reduce lrun within wave (full sum over this wave's kv quarter)
#pragma unroll
  for (int qfi = 0; qfi < 4; qfi++) {
    lrunv[qfi] += __shfl_xor(lrunv[qfi], 16);
    lrunv[qfi] += __shfl_xor(lrunv[qfi], 32);
  }
  __syncthreads();  // all waves done reading K/V; safe to reuse smem
  float* regA = (float*)smem;              // 16KB
  float* regB = (float*)(smem + 16384);    // 16KB
  float* lreg = (float*)(smem + 32768);    // 4KB: wave w at w*256 floats

  // step 1: w1 -> regA, w3 -> regB; all waves publish lrun
  if (w == 1 || w == 3) {
    float* dst = (w == 1) ? regA : regB;
#pragma unroll
    for (int qfi = 0; qfi < 4; qfi++)
#pragma unroll
      for (int dt = 0; dt < 4; dt++)
        *(f32x4*)&dst[(qfi * 4 + dt) * 256 + lane * 4] = acc[qfi][dt];
  }
  *(f32x4*)&lreg[w * 256 + lane * 4] = lrunv;
  __syncthreads();
  // step 2: w0 += w1; w2 += w3
  if (w == 0) {
#pragma unroll
    for (int qfi = 0; qfi < 4; qfi++)
#pragma unroll
      for (int dt = 0; dt < 4; dt++)
        acc[qfi][dt] += *(const f32x4*)&regA[(qfi * 4 + dt) * 256 + lane * 4];
    lrunv += *(const f32x4*)&lreg[1 * 256 + lane * 4];
  } else if (w == 2) {
#pragma unroll
    for (int qfi = 0; qfi < 4; qfi++)
#pragma unroll
      for (int dt = 0; dt < 4; dt++)
        acc[qfi][dt] += *(const f32x4*)&regB[(qfi * 4 + dt) * 256 + lane * 4];
    lrunv += *(const f32x4*)&lreg[3 * 256 + lane * 4];
  }
  __syncthreads();
  // step 3: w2 -> regA (+ its lrun)
  if (w == 2) {
#pragma unroll
    for (int qfi = 0; qfi < 4; qfi++)
#pragma unroll
      for (int dt = 0; dt < 4; dt++)
        *(f32x4*)&regA[(qfi * 4 + dt) * 256 + lane * 4] = acc[qfi][dt];
    *(f32x4*)&lreg[2 * 256 + lane * 4] = lrunv;
  }
  __syncthreads();
  // step 4: w0 += (w2+w3); finalize + store
  if (w == 0) {
#pragma unroll
    for (int qfi = 0; qfi < 4; qfi++)
#pragma unroll
      for (int dt = 0; dt < 4; dt++)
        acc[qfi][dt] += *(const f32x4*)&regA[(qfi * 4 + dt) * 256 + lane * 4];
    lrunv += *(const f32x4*)&lreg[2 * 256 + lane * 4];
#pragma unroll
    for (int qfi = 0; qfi < 4; qfi++) {
      float inv = 1.0f / lrunv[qfi];
      unsigned short* yp = Y + (size_t)(b * 2048 + q0b + qfi * 16 + lo) * 1024 + h * 64;
#pragma unroll
      for (int dt = 0; dt < 4; dt++) {
        float y0 = acc[qfi][dt][0] * inv, y1 = acc[qfi][dt][1] * inv;
        float y2 = acc[qfi][dt][2] * inv, y3 = acc[qfi][dt][3] * inv;
        uint2v pw;
        pw.x = __builtin_amdgcn_perm(__float_as_uint(y1), __float_as_uint(y0), 0x07060302u);
        pw.y = __builtin_amdgcn_perm(__float_as_uint(y3), __float_as_uint(y2), 0x07060302u);
        *(uint2v*)&yp[dt * 16 + g * 4] = pw;
      }
    }
  }
#undef STAGE
#undef COMPUTE
}

// ---------------- launcher ----------------
extern "C" void kernel_launch(void* const* d_in, const int* in_sizes, int n_in,
                              void* d_out, int out_size, void* d_ws, size_t ws_size,
                              hipStream_t stream) {
  const float* x = (const float*)d_in[0];
  const float* wq_lat = (const float*)d_in[1];
  const float* wk_lat = (const float*)d_in[2];
  const float* wv_lat = (const float*)d_in[3];
  const float* wq_h = (const float*)d_in[4];
  const float* wk_h = (const float*)d_in[5];
  const float* wv_h = (const float*)d_in[6];
  const float* w_proj = (const float*)d_in[7];
  const float* b_proj = (const float*)d_in[8];
  float* out = (float*)d_out;

  char* ws = (char*)d_ws;
  unsigned short* x_bf = (unsigned short*)(ws + 0);          // [4096][1024]
  unsigned short* wlatT = (unsigned short*)(ws + 8388608);   // 3 x [256][1024]
  unsigned short* whT = (unsigned short*)(ws + 9961472);     // 3 x [1024][256]
  unsigned short* wpT = (unsigned short*)(ws + 11534336);    // [1024][1024]
  unsigned short* lat = (unsigned short*)(ws + 13631488);    // 3 x [4096][256]
  unsigned short* q_bf = (unsigned short*)(ws + 19922944);   // [4096][1024]
  unsigned short* k_bf = (unsigned short*)(ws + 28311552);   // [4096][1024]
  unsigned short* vT = (unsigned short*)(ws + 36700160);     // [2][16][64][2048]
  unsigned short* y_bf = (unsigned short*)(ws + 45088768);   // [4096][1024]

  prep<<<3584, 256, 0, stream>>>(x, wq_lat, wk_lat, wv_lat, wq_h, wk_h, wv_h, w_proj,
                                 x_bf, wlatT, whT, wpT);

  // stage 1: lat[z] = x @ wlat[z]  (M=4096, N=256, K=1024)
  gemm_bt<0><<<dim3(2, 32, 3), 256, 0, stream>>>(
      x_bf, x_bf, x_bf, wlatT, wlatT + 262144, wlatT + 524288,
      lat, lat + 1048576, lat + 2097152, nullptr, 4096, 256, 1024);

  // stage 2: q/k/vT = lat[z] @ wh[z]  (256^2 8-phase, K=256; Q pre-scaled by SL)
  gemm_up8<<<192, 512, 0, stream>>>(lat, whT, q_bf, k_bf, vT);

  attn_fwd<<<1024, 256, 0, stream>>>(q_bf, k_bf, vT, y_bf);

  gemm_bt<2><<<dim3(8, 32, 1), 256, 0, stream>>>(
      y_bf, y_bf, y_bf, wpT, wpT, wpT, out, out, out, b_proj, 4096, 1024, 1024);
}

// Round 15
// 98.564 us; speedup vs baseline: 1.2051x; 1.2051x over previous
//
#include <hip/hip_runtime.h>

// MLA forward: B=2, T=2048, C=1024, LAT=256, H=16, D=64, causal, SCALE=1/8
#define SCALE 0.125f
#define SL 0.18033688011112042f  // SCALE * log2(e); folded into Q at up-projection

typedef __bf16 bf16x8 __attribute__((ext_vector_type(8)));
typedef short short4v __attribute__((ext_vector_type(4)));
typedef unsigned short u16x4 __attribute__((ext_vector_type(4)));
typedef float f32x4 __attribute__((ext_vector_type(4)));
typedef unsigned int uint2v __attribute__((ext_vector_type(2)));

__device__ __forceinline__ unsigned short f2b(float f) {
  unsigned u = __float_as_uint(f);
  u += 0x7fffu + ((u >> 16) & 1u);   // RNE; inputs here never NaN
  return (unsigned short)(u >> 16);
}
__device__ __forceinline__ float ex2(float x) {  // raw v_exp_f32 (2^x); -3e38 -> +0
  float r;
  asm("v_exp_f32 %0, %1" : "=v"(r) : "v"(x));
  return r;
}

#define GLB(p) ((__attribute__((address_space(1))) void*)(void*)(p))
#define LDSP(p) ((__attribute__((address_space(3))) void*)(p))

// ---------------- fused preprocessing (all weights transposed) ----------------
__global__ __launch_bounds__(256) void prep(
    const float* __restrict__ x, const float* __restrict__ wq_lat,
    const float* __restrict__ wk_lat, const float* __restrict__ wv_lat,
    const float* __restrict__ wq_h, const float* __restrict__ wk_h,
    const float* __restrict__ wv_h, const float* __restrict__ w_proj,
    unsigned short* __restrict__ x_bf, unsigned short* __restrict__ wlatT,
    unsigned short* __restrict__ whT, unsigned short* __restrict__ wpT) {
  __shared__ float tile[32][33];
  const int blk = blockIdx.x, tid = threadIdx.x;
  if (blk < 1024) {  // cast x: 4096x1024 fp32 -> bf16
    int i = blk * 256 + tid;
#pragma unroll
    for (int j = 0; j < 4; j++) {
      float4 v = ((const float4*)x)[i + j * 262144];
      u16x4 p;
      p.x = f2b(v.x); p.y = f2b(v.y); p.z = f2b(v.z); p.w = f2b(v.w);
      ((u16x4*)x_bf)[i + j * 262144] = p;
    }
  } else if (blk < 1792) {  // transpose wlat: [1024][256] -> wlatT[256][1024], x3
    int idx = blk - 1024;
    int z = idx >> 8, rem = idx & 255;
    const float* wsrc = z == 0 ? wq_lat : (z == 1 ? wk_lat : wv_lat);
    unsigned short* o = wlatT + z * 262144;
    int c0 = (rem & 7) * 32, r0 = (rem >> 3) * 32;
    int tx = tid & 31, ty = tid >> 5;
#pragma unroll
    for (int i = 0; i < 32; i += 8) tile[ty + i][tx] = wsrc[(r0 + ty + i) * 256 + c0 + tx];
    __syncthreads();
#pragma unroll
    for (int i = 0; i < 32; i += 8) o[(c0 + ty + i) * 1024 + r0 + tx] = f2b(tile[tx][ty + i]);
  } else if (blk < 2560) {  // transpose heads: [256][1024] -> whT[1024][256], x3
    int idx = blk - 1792;
    int z = idx >> 8, rem = idx & 255;
    const float* wsrc = z == 0 ? wq_h : (z == 1 ? wk_h : wv_h);
    unsigned short* o = whT + z * 262144;
    int c0 = (rem & 31) * 32, r0 = (rem >> 5) * 32;
    int tx = tid & 31, ty = tid >> 5;
#pragma unroll
    for (int i = 0; i < 32; i += 8) tile[ty + i][tx] = wsrc[(r0 + ty + i) * 1024 + c0 + tx];
    __syncthreads();
#pragma unroll
    for (int i = 0; i < 32; i += 8) o[(c0 + ty + i) * 256 + r0 + tx] = f2b(tile[tx][ty + i]);
  } else {  // transpose wproj: [1024][1024] -> wpT
    int idx = blk - 2560;
    int c0 = (idx & 31) * 32, r0 = (idx >> 5) * 32;
    int tx = tid & 31, ty = tid >> 5;
#pragma unroll
    for (int i = 0; i < 32; i += 8) tile[ty + i][tx] = w_proj[(r0 + ty + i) * 1024 + c0 + tx];
    __syncthreads();
#pragma unroll
    for (int i = 0; i < 32; i += 8) wpT[(c0 + ty + i) * 1024 + r0 + tx] = f2b(tile[tx][ty + i]);
  }
}

// ---------------- GEMM (T3-minimum 2-phase pipeline): C[M,N] = A * BT^T ----------------
// Double-buffered LDS; STAGE(next) issued BEFORE compute(cur); one vmcnt(0)+barrier per
// K-step (same discipline as the validated up8/qkv8 kernels). K must be divisible by 64.
template <int MODE>  // 0: bf16 out; 2: fp32 out + bias
__global__ __launch_bounds__(256) void gemm_bt(
    const unsigned short* __restrict__ A0, const unsigned short* __restrict__ A1,
    const unsigned short* __restrict__ A2,
    const unsigned short* __restrict__ B0, const unsigned short* __restrict__ B1,
    const unsigned short* __restrict__ B2,
    void* __restrict__ C0, void* __restrict__ C1, void* __restrict__ C2,
    const float* __restrict__ bias, int M, int N, int K) {
  const int z = blockIdx.z;
  const unsigned short* A = z == 0 ? A0 : (z == 1 ? A1 : A2);
  const unsigned short* BT = z == 0 ? B0 : (z == 1 ? B1 : B2);
  void* C = z == 0 ? C0 : (z == 1 ? C1 : C2);

  __shared__ char smem[32768];  // A0|A1 @0,8K; B0|B1 @16K,24K

  const int t = threadIdx.x;
  const int n0 = blockIdx.x * 128;
  const int m0 = blockIdx.y * 128;
  const int lane = t & 63;
  const int wid = t >> 6;
  const int wr = wid >> 1, wc = wid & 1;
  const int lo = lane & 15, g = lane >> 4;

  f32x4 acc[4][4];
#pragma unroll
  for (int i = 0; i < 4; i++)
#pragma unroll
    for (int j = 0; j < 4; j++) acc[i][j] = (f32x4){0.f, 0.f, 0.f, 0.f};

  const unsigned short* ga = A + (size_t)(m0 + (t >> 2)) * K + (t & 3) * 8;
  const unsigned short* gb = BT + (size_t)(n0 + (t >> 2)) * K + (t & 3) * 8;
  const size_t rowK64 = (size_t)64 * K;
  char* dA = smem + t * 16;
  char* dB = smem + 16384 + t * 16;
  const char* rA = smem + (wr * 64 + lo) * 64 + g * 16;
  const char* rB = smem + 16384 + (wc * 64 + lo) * 64 + g * 16;

#define STGB(D, kof)                                                                     \
  __builtin_amdgcn_global_load_lds(GLB(ga + (kof)), LDSP(dA + (D)*8192), 16, 0, 0);      \
  __builtin_amdgcn_global_load_lds(GLB(ga + rowK64 + (kof)), LDSP(dA + (D)*8192 + 4096), 16, 0, 0); \
  __builtin_amdgcn_global_load_lds(GLB(gb + (kof)), LDSP(dB + (D)*8192), 16, 0, 0);      \
  __builtin_amdgcn_global_load_lds(GLB(gb + rowK64 + (kof)), LDSP(dB + (D)*8192 + 4096), 16, 0, 0);

#define COMPB(D)                                                                         \
  {                                                                                      \
    bf16x8 af[4], bfr[4];                                                                \
    _Pragma("unroll") for (int i = 0; i < 4; i++) {                                      \
      af[i] = *(const bf16x8*)(rA + (D)*8192 + i * 1024);                                \
      bfr[i] = *(const bf16x8*)(rB + (D)*8192 + i * 1024);                               \
    }                                                                                    \
    __builtin_amdgcn_s_setprio(1);                                                       \
    _Pragma("unroll") for (int i = 0; i < 4; i++)                                        \
    _Pragma("unroll") for (int j = 0; j < 4; j++)                                        \
        acc[i][j] = __builtin_amdgcn_mfma_f32_16x16x32_bf16(af[i], bfr[j], acc[i][j], 0, 0, 0); \
    __builtin_amdgcn_s_setprio(0);                                                       \
  }

  STGB(0, 0);
  asm volatile("s_waitcnt vmcnt(0)" ::: "memory");
  __builtin_amdgcn_s_barrier();
  for (int k0 = 0; k0 < K; k0 += 64) {
    if (k0 + 32 < K) { STGB(1, k0 + 32); }
    COMPB(0);
    asm volatile("s_waitcnt vmcnt(0)" ::: "memory");
    __builtin_amdgcn_s_barrier();
    if (k0 + 64 < K) { STGB(0, k0 + 64); }
    COMPB(1);
    asm volatile("s_waitcnt vmcnt(0)" ::: "memory");
    __builtin_amdgcn_s_barrier();
  }
#undef STGB
#undef COMPB

  if constexpr (MODE == 2) {
    float* Cf = (float*)C;
#pragma unroll
    for (int i = 0; i < 4; i++) {
      int row0 = m0 + wr * 64 + i * 16 + g * 4;
#pragma unroll
      for (int j = 0; j < 4; j++) {
        int col = n0 + wc * 64 + j * 16 + lo;
        float bv = bias[col];
#pragma unroll
        for (int r = 0; r < 4; r++) Cf[(size_t)(row0 + r) * N + col] = acc[i][j][r] + bv;
      }
    }
  } else {
    unsigned short* Cb = (unsigned short*)C;
#pragma unroll
    for (int i = 0; i < 4; i++) {
      int row0 = m0 + wr * 64 + i * 16 + g * 4;
#pragma unroll
      for (int j = 0; j < 4; j++) {
        int col = n0 + wc * 64 + j * 16 + lo;
#pragma unroll
        for (int r = 0; r < 4; r++) Cb[(size_t)(row0 + r) * N + col] = f2b(acc[i][j][r]);
      }
    }
  }
}

// ---------------- 256x256 8-phase up-projection GEMM (K=256, NT=4 K-tiles) ----------------
__global__ __launch_bounds__(512) void gemm_up8(const unsigned short* __restrict__ A,
                                                const unsigned short* __restrict__ BT,
                                                unsigned short* __restrict__ Qo,
                                                unsigned short* __restrict__ Ko,
                                                unsigned short* __restrict__ Vo) {
  __shared__ char smem[131072];  // [dbuf][A0|A1|B0|B1] quarters of 16KB ([256 rows][64B])

  const int t = threadIdx.x;            // 0..511
  const int lane = t & 63;
  const int wid = t >> 6;               // 0..7
  const int wr = wid >> 2, wc = wid & 3;
  const int lo = lane & 15, g = lane >> 4;
  const int lin = blockIdx.x;           // 0..191
  const int xcd = lin & 7;
  const int slot = lin >> 3;            // 0..23
  const int by = (xcd << 1) | (slot >= 12 ? 1 : 0);
  const int bx = slot >= 12 ? slot - 12 : slot;   // 0..11
  const int m0 = by * 256;
  const int z = bx >> 2;                // 0:Q 1:K 2:V
  const int ncb = (bx & 3) * 256;
  const unsigned short* Az = A + (size_t)z * 1048576;   // lat z-slice [4096][256]
  const unsigned short* Bz = BT + (size_t)z * 262144;   // whT z-slice [1024][256]

  const int slog8 = (((t & 3) ^ ((t >> 2) & 3) ^ (((t >> 4) & 1) << 1)) << 3);
  const unsigned short *aS00, *aS01, *aS10, *aS11, *bS00, *bS01, *bS10, *bS11;
  {
    const int r = t >> 2;
    aS00 = Az + (size_t)(m0 + r) * 256 + slog8;
    aS01 = Az + (size_t)(m0 + r + 128) * 256 + slog8;
    aS10 = aS00 + 32;
    aS11 = aS01 + 32;
    bS00 = Bz + (size_t)(ncb + r) * 256 + slog8;
    bS01 = Bz + (size_t)(ncb + r + 128) * 256 + slog8;
    bS10 = bS00 + 32;
    bS11 = bS01 + 32;
  }
  char* dA0 = smem + t * 16;
  char* dA1 = smem + 16384 + t * 16;
  char* dB0 = smem + 32768 + t * 16;
  char* dB1 = smem + 49152 + t * 16;

  const int slotA = ((g ^ (lo & 3) ^ (((lo >> 2) & 1) << 1)) << 4);
  const char* aR = smem + (wr * 128 + lo) * 64 + slotA;
  const char* bR = smem + 32768 + (wc * 64 + lo) * 64 + slotA;

  f32x4 acc[8][4];
#pragma unroll
  for (int i = 0; i < 8; i++)
#pragma unroll
    for (int j = 0; j < 4; j++) acc[i][j] = (f32x4){0.f, 0.f, 0.f, 0.f};

#define STG(p0, p1, dst, D)                                                              \
  __builtin_amdgcn_global_load_lds(GLB(p0), LDSP(dst + (D)*65536), 16, 0, 0);            \
  __builtin_amdgcn_global_load_lds(GLB(p1), LDSP(dst + (D)*65536 + 8192), 16, 0, 0);     \
  p0 += 64; p1 += 64;

#define MF16(FRB, af, bf)                                                                \
  __builtin_amdgcn_s_setprio(1);                                                         \
  _Pragma("unroll") for (int i = 0; i < 4; i++)                                          \
  _Pragma("unroll") for (int j = 0; j < 4; j++)                                          \
      acc[(FRB) + i][j] = __builtin_amdgcn_mfma_f32_16x16x32_bf16(af[i], bf[j],          \
                                                                  acc[(FRB) + i][j], 0, 0, 0); \
  __builtin_amdgcn_s_setprio(0);

#define TILE(D, S)                                                                       \
  {                                                                                      \
    bf16x8 af[4], bf[4];                                                                 \
    _Pragma("unroll") for (int j = 0; j < 4; j++)                                        \
        bf[j] = *(const bf16x8*)(bR + (D)*65536 + j * 1024);                             \
    _Pragma("unroll") for (int i = 0; i < 4; i++)                                        \
        af[i] = *(const bf16x8*)(aR + (D)*65536 + i * 1024);                             \
    if (S) { STG(aS00, aS01, dA0, (D) ^ 1); }                                            \
    __builtin_amdgcn_s_barrier();                                                        \
    MF16(0, af, bf);                                                                     \
    __builtin_amdgcn_s_barrier();                                                        \
    _Pragma("unroll") for (int i = 0; i < 4; i++)                                        \
        af[i] = *(const bf16x8*)(aR + (D)*65536 + (4 + i) * 1024);                       \
    if (S) { STG(bS00, bS01, dB0, (D) ^ 1); }                                            \
    __builtin_amdgcn_s_barrier();                                                        \
    MF16(4, af, bf);                                                                     \
    if (S) { asm volatile("s_waitcnt vmcnt(4)" ::: "memory"); }                          \
    else   { asm volatile("s_waitcnt vmcnt(0)" ::: "memory"); }                          \
    __builtin_amdgcn_s_barrier();                                                        \
    _Pragma("unroll") for (int j = 0; j < 4; j++)                                        \
        bf[j] = *(const bf16x8*)(bR + (D)*65536 + 16384 + j * 1024);                     \
    _Pragma("unroll") for (int i = 0; i < 4; i++)                                        \
        af[i] = *(const bf16x8*)(aR + (D)*65536 + 16384 + i * 1024);                     \
    if (S) { STG(aS10, aS11, dA1, (D) ^ 1); }                                            \
    __builtin_amdgcn_s_barrier();                                                        \
    MF16(0, af, bf);                                                                     \
    __builtin_amdgcn_s_barrier();                                                        \
    _Pragma("unroll") for (int i = 0; i < 4; i++)                                        \
        af[i] = *(const bf16x8*)(aR + (D)*65536 + 16384 + (4 + i) * 1024);               \
    if (S) { STG(bS10, bS11, dB1, (D) ^ 1); }                                            \
    __builtin_amdgcn_s_barrier();                                                        \
    MF16(4, af, bf);                                                                     \
    if (S) { asm volatile("s_waitcnt vmcnt(4)" ::: "memory"); }                          \
    __builtin_amdgcn_s_barrier();                                                        \
  }

  { STG(aS00, aS01, dA0, 0); }
  { STG(bS00, bS01, dB0, 0); }
  { STG(aS10, aS11, dA1, 0); }
  { STG(bS10, bS11, dB1, 0); }
  asm volatile("s_waitcnt vmcnt(0)" ::: "memory");
  __builtin_amdgcn_s_barrier();

  // 4 K-tiles (K=256, BK=64): tiles 0..2 stage the next; tile 3 drains
  TILE(0, 1);
  TILE(1, 1);
  TILE(0, 1);
  TILE(1, 0);

#undef TILE
#undef MF16
#undef STG

  if (z < 2) {
    unsigned short* Cb = z == 0 ? Qo : Ko;
    const float scl = z == 0 ? SL : 1.0f;   // fold SCALE*log2e into Q
#pragma unroll
    for (int fr = 0; fr < 8; fr++) {
      int row0 = m0 + wr * 128 + fr * 16 + g * 4;
#pragma unroll
      for (int fc = 0; fc < 4; fc++) {
        int col = ncb + wc * 64 + fc * 16 + lo;
#pragma unroll
        for (int r = 0; r < 4; r++) Cb[(size_t)(row0 + r) * 1024 + col] = f2b(acc[fr][fc][r] * scl);
      }
    }
  } else {
#pragma unroll
    for (int fr = 0; fr < 8; fr++) {
      int row0 = m0 + wr * 128 + fr * 16 + g * 4;
      int bb = row0 >> 11, tloc = row0 & 2047;
#pragma unroll
      for (int fc = 0; fc < 4; fc++) {
        int col = ncb + wc * 64 + fc * 16 + lo;
        u16x4 pk;
#pragma unroll
        for (int r = 0; r < 4; r++) pk[r] = f2b(acc[fr][fc][r]);
        *(u16x4*)&Vo[((size_t)(bb * 1024) + col) * 2048 + tloc] = pk;
      }
    }
  }
}

// ---------------- flash attention (R13 best): static-max softmax, native exp ----------
// Q pre-scaled by SCALE*log2e -> S^T = mfma(K,Q) emits exp2-ready args; |S| < ~0.4 so a
// static max of 0 is safe. exp via raw v_exp_f32; each kvf's exps+pack feed its 4 PV
// MFMAs immediately (exp(kvf+1) overlaps MFMA(kvf)). 1024 blocks x 4 waves, QBLK=16.
__global__ __launch_bounds__(256) void attn_fwd(const unsigned short* __restrict__ Q,
                                                const unsigned short* __restrict__ K,
                                                const unsigned short* __restrict__ VT,
                                                unsigned short* __restrict__ Y) {
  __shared__ char smem[32768];  // lK[2][8KB] | lV[2][8KB]

  const int tid = threadIdx.x;
  const int w = tid >> 6;
  const int lane = tid & 63;
  const int lo = lane & 15, g = lane >> 4;
  const int lo7 = lo & 7;
  const int bid = blockIdx.x;
  const int bh = bid & 31;       // (b,h) -> fixed XCD (bid%8)
  const int code = bid >> 5;     // 0..31
  const int qq = code >> 3, kk = code & 7;
  // per-CU balanced: chunks {31-k, 16+k, 15-k, k} sum to 62 for all k
  const int chunk = qq == 0 ? 31 - kk : (qq == 1 ? 16 + kk : (qq == 2 ? 15 - kk : kk));
  const int b = bh >> 4, h = bh & 15;
  const int q0 = chunk * 64 + w * 16;

  const unsigned short* Qb = Q + (size_t)(b * 2048) * 1024 + h * 64;
  const unsigned short* Kb = K + (size_t)(b * 2048) * 1024 + h * 64;
  const unsigned short* Vb = VT + (size_t)((b * 16 + h) * 64) * 2048;

  bf16x8 qf0 = *(const bf16x8*)(Qb + (size_t)(q0 + lo) * 1024 + g * 8);
  bf16x8 qf1 = *(const bf16x8*)(Qb + (size_t)(q0 + lo) * 1024 + 32 + g * 8);

  const f32x4 z4 = (f32x4){0.f, 0.f, 0.f, 0.f};  // hoisted MFMA C-operand
  f32x4 acc[4];
#pragma unroll
  for (int dt = 0; dt < 4; dt++) acc[dt] = z4;
  float lrun = 0.f;
  const int nt = chunk + 1;

  const int koff = lo * 128 + ((g ^ lo7) << 4);
  char* kb0 = smem + koff;
  char* kb1 = smem + (koff ^ 64);
  const int voff = lo * 128 + ((g ^ ((lo7 & 1) << 1)) << 3) + ((lo7 >> 1) << 5);
  char* vq0 = smem + 16384 + voff;
  char* vq1 = smem + 16384 + (voff ^ 32);
  char* vq2 = smem + 16384 + (voff ^ 64);
  char* vq3 = smem + 16384 + (voff ^ 96);

  const int r0s = tid >> 3, c0s = (tid & 7) ^ (r0s & 7);
  const unsigned short* sk0 = Kb + (size_t)r0s * 1024 + c0s * 8;
  const unsigned short* sk1 = sk0 + (size_t)32 * 1024;
  const unsigned short* sv0 = Vb + (size_t)r0s * 2048 + c0s * 8;
  const unsigned short* sv1 = sv0 + (size_t)32 * 2048;
  char* dk0 = smem + tid * 16;
  char* dk1 = smem + 4096 + tid * 16;
  char* dv0 = smem + 16384 + tid * 16;
  char* dv1 = smem + 20480 + tid * 16;

#define STAGE(BUF)                                                                        \
  __builtin_amdgcn_global_load_lds(GLB(sk0), LDSP(dk0 + (BUF)*8192), 16, 0, 0);           \
  __builtin_amdgcn_global_load_lds(GLB(sk1), LDSP(dk1 + (BUF)*8192), 16, 0, 0);           \
  __builtin_amdgcn_global_load_lds(GLB(sv0), LDSP(dv0 + (BUF)*8192), 16, 0, 0);           \
  __builtin_amdgcn_global_load_lds(GLB(sv1), LDSP(dv1 + (BUF)*8192), 16, 0, 0);           \
  sk0 += 65536; sk1 += 65536; sv0 += 64; sv1 += 64;

#define COMPUTE(k0v, BUF, MASKED)                                                         \
  {                                                                                       \
    bf16x8 kfA[4], kfB[4];                                                                \
    _Pragma("unroll") for (int kvf = 0; kvf < 4; kvf++) {                                 \
      kfA[kvf] = *(const bf16x8*)(kb0 + (BUF)*8192 + kvf * 2048);                         \
      kfB[kvf] = *(const bf16x8*)(kb1 + (BUF)*8192 + kvf * 2048);                         \
    }                                                                                     \
    short4v vf[4][4];                                                                     \
    _Pragma("unroll") for (int kvf = 0; kvf < 4; kvf++) {                                 \
      const char* vp = kvf == 0 ? vq0 : (kvf == 1 ? vq1 : (kvf == 2 ? vq2 : vq3));        \
      _Pragma("unroll") for (int dt = 0; dt < 4; dt++)                                    \
          vf[dt][kvf] = *(const short4v*)(vp + (BUF)*8192 + dt * 2048);                   \
    }                                                                                     \
    f32x4 st[4];                                                                          \
    __builtin_amdgcn_s_setprio(1);                                                        \
    _Pragma("unroll") for (int kvf = 0; kvf < 4; kvf++) {                                 \
      st[kvf] = __builtin_amdgcn_mfma_f32_16x16x32_bf16(kfA[kvf], qf0, z4, 0, 0, 0);      \
      st[kvf] = __builtin_amdgcn_mfma_f32_16x16x32_bf16(kfB[kvf], qf1, st[kvf], 0, 0, 0); \
    }                                                                                     \
    __builtin_amdgcn_s_setprio(0);                                                        \
    if (MASKED) {                                                                         \
      const int qg = q0 + lo;                                                             \
      _Pragma("unroll") for (int kvf = 0; kvf < 4; kvf++)                                 \
      _Pragma("unroll") for (int r = 0; r < 4; r++) {                                     \
        int tk = (k0v) + kvf * 16 + g * 4 + r;                                            \
        if (tk > qg) st[kvf][r] = -3.0e38f;                                               \
      }                                                                                   \
    }                                                                                     \
    __builtin_amdgcn_s_setprio(1);                                                        \
    _Pragma("unroll") for (int kvf = 0; kvf < 4; kvf++) {                                 \
      float p0 = ex2(st[kvf][0]);                                                         \
      float p1 = ex2(st[kvf][1]);                                                         \
      float p2 = ex2(st[kvf][2]);                                                         \
      float p3 = ex2(st[kvf][3]);                                                         \
      lrun += (p0 + p1) + (p2 + p3);                                                      \
      uint2v pw;                                                                          \
      pw.x = __builtin_amdgcn_perm(__float_as_uint(p1), __float_as_uint(p0), 0x07060302u); \
      pw.y = __builtin_amdgcn_perm(__float_as_uint(p3), __float_as_uint(p2), 0x07060302u); \
      short4v pb = __builtin_bit_cast(short4v, pw);                                       \
      _Pragma("unroll") for (int dt = 0; dt < 4; dt++)                                    \
          acc[dt] = __builtin_amdgcn_mfma_f32_16x16x16bf16_1k(vf[dt][kvf], pb,            \
                                                              acc[dt], 0, 0, 0);          \
    }                                                                                     \
    __builtin_amdgcn_s_setprio(0);                                                        \
  }

  STAGE(0);
  __syncthreads();
  int t = 0;
  for (; t + 2 <= nt - 1; t += 2) {
    STAGE(1);
    COMPUTE(t * 64, 0, false);
    __syncthreads();
    STAGE(0);
    COMPUTE(t * 64 + 64, 1, false);
    __syncthreads();
  }
  if (t < nt - 1) {
    STAGE(1);
    COMPUTE(t * 64, 0, false);
    __syncthreads();
    COMPUTE(t * 64 + 64, 1, true);
  } else {
    COMPUTE(t * 64, 0, true);
  }

  {
    float l = lrun;
    l += __shfl_xor(l, 16);
    l += __shfl_xor(l, 32);
    float inv = 1.0f / l;
    unsigned short* yp = Y + (size_t)(b * 2048 + q0 + lo) * 1024 + h * 64;
#pragma unroll
    for (int dt = 0; dt < 4; dt++) {
      float y0 = acc[dt][0] * inv, y1 = acc[dt][1] * inv;
      float y2 = acc[dt][2] * inv, y3 = acc[dt][3] * inv;
      uint2v pw;
      pw.x = __builtin_amdgcn_perm(__float_as_uint(y1), __float_as_uint(y0), 0x07060302u);
      pw.y = __builtin_amdgcn_perm(__float_as_uint(y3), __float_as_uint(y2), 0x07060302u);
      *(uint2v*)&yp[dt * 16 + g * 4] = pw;
    }
  }
#undef STAGE
#undef COMPUTE
}

// ---------------- launcher ----------------
extern "C" void kernel_launch(void* const* d_in, const int* in_sizes, int n_in,
                              void* d_out, int out_size, void* d_ws, size_t ws_size,
                              hipStream_t stream) {
  const float* x = (const float*)d_in[0];
  const float* wq_lat = (const float*)d_in[1];
  const float* wk_lat = (const float*)d_in[2];
  const float* wv_lat = (const float*)d_in[3];
  const float* wq_h = (const float*)d_in[4];
  const float* wk_h = (const float*)d_in[5];
  const float* wv_h = (const float*)d_in[6];
  const float* w_proj = (const float*)d_in[7];
  const float* b_proj = (const float*)d_in[8];
  float* out = (float*)d_out;

  char* ws = (char*)d_ws;
  unsigned short* x_bf = (unsigned short*)(ws + 0);          // [4096][1024]
  unsigned short* wlatT = (unsigned short*)(ws + 8388608);   // 3 x [256][1024]
  unsigned short* whT = (unsigned short*)(ws + 9961472);     // 3 x [1024][256]
  unsigned short* wpT = (unsigned short*)(ws + 11534336);    // [1024][1024]
  unsigned short* lat = (unsigned short*)(ws + 13631488);    // 3 x [4096][256]
  unsigned short* q_bf = (unsigned short*)(ws + 19922944);   // [4096][1024]
  unsigned short* k_bf = (unsigned short*)(ws + 28311552);   // [4096][1024]
  unsigned short* vT = (unsigned short*)(ws + 36700160);     // [2][16][64][2048]
  unsigned short* y_bf = (unsigned short*)(ws + 45088768);   // [4096][1024]

  prep<<<3584, 256, 0, stream>>>(x, wq_lat, wk_lat, wv_lat, wq_h, wk_h, wv_h, w_proj,
                                 x_bf, wlatT, whT, wpT);

  // stage 1: lat[z] = x @ wlat[z]  (M=4096, N=256, K=1024)
  gemm_bt<0><<<dim3(2, 32, 3), 256, 0, stream>>>(
      x_bf, x_bf, x_bf, wlatT, wlatT + 262144, wlatT + 524288,
      lat, lat + 1048576, lat + 2097152, nullptr, 4096, 256, 1024);

  // stage 2: q/k/vT = lat[z] @ wh[z]  (256^2 8-phase, K=256; Q pre-scaled by SL)
  gemm_up8<<<192, 512, 0, stream>>>(lat, whT, q_bf, k_bf, vT);

  attn_fwd<<<1024, 256, 0, stream>>>(q_bf, k_bf, vT, y_bf);

  gemm_bt<2><<<dim3(8, 32, 1), 256, 0, stream>>>(
      y_bf, y_bf, y_bf, wpT, wpT, wpT, out, out, out, b_proj, 4096, 1024, 1024);
}